// Round 12
// baseline (135.014 us; speedup 1.0000x reference)
//
#include <hip/hip_runtime.h>

typedef unsigned short u16;
typedef unsigned int u32;
typedef short s16x8 __attribute__((ext_vector_type(8)));
typedef float f32x4 __attribute__((ext_vector_type(4)));
typedef u32 u32x4 __attribute__((ext_vector_type(4)));
typedef int i32x8 __attribute__((ext_vector_type(8)));

// ---- workspace byte offsets ----
// uT/vT: [b][h][k] bf16 (u includes b1); W2F8: sigma'-permuted W2^T fp8; e_raw f32
#define UT_D   0u
#define VT_D   524288u
#define UT_N   1048576u
#define VT_N   1572864u
#define W2F8_D 2097152u
#define W2F8_N 2113536u
#define ERAW   2162688u

#define SCALE1 0x7F7F7F7F   // E8M0 = 127 in every byte -> scale factor 1.0

__device__ __forceinline__ u16 f2bf(float x) {
  u32 u = __float_as_uint(x);
  return (u16)((u + 0x7FFFu + ((u >> 16) & 1u)) >> 16);   // RNE
}
__device__ __forceinline__ u32 cvt_pk_bf16(float lo, float hi) {
  u32 r;
  asm("v_cvt_pk_bf16_f32 %0, %1, %2" : "=v"(r) : "v"(lo), "v"(hi));
  return r;
}
__device__ __forceinline__ s16x8 as_frag(u32x4 v) { return __builtin_bit_cast(s16x8, v); }

// =====================================================================
// kernel 1 (merged): blocks x<128: per-agent layer-1 projections, 16 agents
// per block (W1 L2 traffic halved vs 8-agent). block x==128: fp8 W2^T staging.
// sigma': k = 32g + 4m + r  <->  h = 16m + 4g + r
__global__ __launch_bounds__(256) void k_uvw(
    const float* __restrict__ af, const float* __restrict__ zm, const float* __restrict__ zlv,
    const float* __restrict__ W1d, const float* __restrict__ b1d,
    const float* __restrict__ W1n, const float* __restrict__ b1n,
    const float* __restrict__ W2d, const float* __restrict__ W2n,
    u16* __restrict__ ws16) {
  const int mlp = blockIdx.y;
  const int t   = threadIdx.x;
  if (blockIdx.x == 128) {
    const float* W2 = mlp ? W2n : W2d;
    u16* W2s8 = (u16*)((char*)ws16 + (mlp ? W2F8_N : W2F8_D));   // [nn][k] fp8, u16 pairs
    for (int idx = t; idx < 8192; idx += 256) {
      const int nn = idx >> 6, k2 = idx & 63, k = 2*k2;
      const int g = k >> 5, m = (k >> 2) & 7, r = k & 3;
      const int h0 = 16*m + 4*g + r;
      const u32 pk = (u32)__builtin_amdgcn_cvt_pk_fp8_f32(W2[h0*128 + nn], W2[(h0+1)*128 + nn], 0, false);
      W2s8[nn*64 + k2] = (u16)(pk & 0xFFFFu);
    }
    return;
  }
  const int a0 = blockIdx.x * 16;
  __shared__ float xs[16][128];
  for (int idx = t; idx < 2048; idx += 256) {
    const int a = idx >> 7, f = idx & 127, ga = a0 + a;
    float v;
    if (f < 64)      v = af[ga*64 + f];
    else if (f < 96) v = zm[ga*32 + (f-64)];
    else             v = zlv[ga*32 + (f-96)];
    xs[a][f] = v;
  }
  __syncthreads();
  const int h = t & 127, half = t >> 7;
  const float* W1 = mlp ? W1n : W1d;
  const int aoff = (mlp ? 5 : 0) + 64*half;
  const int zoff = 69 + 64*half;
  float acc[16];
  #pragma unroll
  for (int a = 0; a < 16; ++a) acc[a] = 0.f;
  #pragma unroll 2
  for (int f = 0; f < 64; f += 4) {
    const float w0 = W1[(aoff+f  )*128 + h];
    const float w1 = W1[(aoff+f+1)*128 + h];
    const float w2 = W1[(aoff+f+2)*128 + h];
    const float w3 = W1[(aoff+f+3)*128 + h];
    #pragma unroll
    for (int a = 0; a < 16; ++a) {
      const f32x4 xv = *(const f32x4*)&xs[a][f];
      acc[a] = fmaf(xv[3], w3, fmaf(xv[2], w2, fmaf(xv[1], w1, fmaf(xv[0], w0, acc[a]))));
    }
  }
  #pragma unroll 2
  for (int f = 64; f < 128; f += 4) {
    const float w0 = W1[(zoff+f  )*128 + h];
    const float w1 = W1[(zoff+f+1)*128 + h];
    const float w2 = W1[(zoff+f+2)*128 + h];
    const float w3 = W1[(zoff+f+3)*128 + h];
    #pragma unroll
    for (int a = 0; a < 16; ++a) {
      const f32x4 xv = *(const f32x4*)&xs[a][f];
      acc[a] = fmaf(xv[3], w3, fmaf(xv[2], w2, fmaf(xv[1], w1, fmaf(xv[0], w0, acc[a]))));
    }
  }
  const float bb = half ? 0.f : (mlp ? b1n[h] : b1d[h]);
  u16 pk[16];
  #pragma unroll
  for (int a = 0; a < 16; ++a) pk[a] = f2bf(acc[a] + bb);
  const int b = a0 >> 8;
  u16* dT = (u16*)((char*)ws16 + (mlp ? (half ? VT_N : UT_N) : (half ? VT_D : UT_D)));
  *(s16x8*)(dT + (b*128 + h)*256 + (a0 & 255))     = *(s16x8*)&pk[0];
  *(s16x8*)(dT + (b*128 + h)*256 + (a0 & 255) + 8) = *(s16x8*)&pk[8];
}

// =====================================================================
// kernel 2: main == R10 (validated, absmax 0.0215) with ONE scheduling
// change: s-loop unroll 2 so the compiler can overlap pass-1(s+1) MFMA
// issue under step-s epilogue VALU + shfl tail (in-wave ILP; occupancy
// path is closed -- R6/R11 both spilled at >2 blocks/CU).
__global__ __launch_bounds__(256, 2) void k_main(
    const float* __restrict__ af, const float* __restrict__ mask,
    const float* __restrict__ W1d, const float* __restrict__ b2d, const float* __restrict__ W3d, const float* __restrict__ b3d,
    const float* __restrict__ W1n, const float* __restrict__ b2n, const float* __restrict__ W3n, const float* __restrict__ b3n,
    const u16* __restrict__ ws16, float* __restrict__ e_raw, float* __restrict__ out) {
  const int t   = threadIdx.x;
  const int i0  = blockIdx.x * 8;
  const int mlp = blockIdx.y & 1, jc = blockIdx.y >> 1;   // jc in 0..1
  const int b   = blockIdx.z;

  __shared__ char  w2l[128*144];   // fp8 W2 sigma', rows padded to 144 B (16 | 144)
  __shared__ float b2w3f[2][128];
  __shared__ float maskF[256];

  // stage W2 fp8 into padded LDS (linear global -> 144B-stride rows)
  {
    const char* w2g = (const char*)ws16 + (mlp ? W2F8_N : W2F8_D);
    const int row = t >> 1, c0 = (t & 1) * 64;
    #pragma unroll
    for (int q = 0; q < 4; ++q) {
      u32x4 v = *(const u32x4*)(w2g + row*128 + c0 + 16*q);
      *(u32x4*)(w2l + row*144 + c0 + 16*q) = v;
    }
  }
  if (t < 128) b2w3f[0][t] = (mlp ? b2n : b2d)[t];
  else         b2w3f[1][t-128] = (mlp ? W3n : W3d)[t-128];
  maskF[t] = mask[b*256 + t];
  const float b3v = (mlp ? b3n : b3d)[0];

  const int wv = t >> 6, l = t & 63, x = l & 15, g = l >> 4;
  const int xh = x >> 3, xl = x & 7;
  const int lanebyte = 144*x + 32*g;   // 16B-aligned for all lanes; +2304*w per tile

  const u16* uT = (const u16*)((const char*)ws16 + (mlp ? UT_N : UT_D));
  const u16* vT = (const u16*)((const char*)ws16 + (mlp ? VT_N : VT_D));
  const float* W1 = mlp ? W1n : W1d;
  const int grow = mlp ? 0 : 128;

  // ---- persistent pass-1 A-frags: g0 = u'_i octet, g1 = v_j (per step),
  //      g2 = 0, g3 = Wg octet ----
  s16x8 Af[8];
  #pragma unroll
  for (int m = 0; m < 8; ++m) {
    u32x4 a = {0u, 0u, 0u, 0u};
    if (g == 0) {
      a = *(const u32x4*)(uT + (b*128 + 16*m + x)*256 + i0);
    } else if (g == 3) {
      const int h = 16*m + x;
      const float w0 = W1[(grow+0)*128 + h], w1 = W1[(grow+1)*128 + h];
      const float w2 = W1[(grow+2)*128 + h], w3 = W1[(grow+3)*128 + h];
      const float w4 = W1[(grow+4)*128 + h];
      a[0] = cvt_pk_bf16(w0, w1); a[1] = cvt_pk_bf16(w2, w3);
      a[2] = cvt_pk_bf16(w4, 0.f); a[3] = 0u;
    }
    Af[m] = __builtin_bit_cast(s16x8, a);
  }

  // ---- static one-hot B-frags (g0: i-onehot, g1: j-onehot); g3 geom/step ----
  u32x4 B1u[4];
  #pragma unroll
  for (int n = 0; n < 4; ++n) {
    u32x4 v = {0u, 0u, 0u, 0u};
    if (g == 0) {
      const int il = 2*n + xh;
      v[il >> 1] = (il & 1) ? 0x3F800000u : 0x3F80u;
    } else if (g == 1) {
      v[xl >> 1] = (xl & 1) ? 0x3F800000u : 0x3F80u;
    }
    B1u[n] = v;
  }

  // ---- i-side geom comps (block-static): 0,1,3,4 of i = i0+2n+xh ----
  f32x4 aic[4];
  #pragma unroll
  for (int n = 0; n < 4; ++n) {
    const float* ap = af + (b*256 + i0 + 2*n + xh)*64;
    aic[n][0] = ap[0]; aic[n][1] = ap[1]; aic[n][2] = ap[3]; aic[n][3] = ap[4];
  }

  int j0w = jc*128 + wv*8;
  if (g == 1) {
    #pragma unroll
    for (int m = 0; m < 8; ++m)
      Af[m] = *(const s16x8*)(vT + (b*128 + 16*m + x)*256 + j0w);
  }
  float aj0, aj1, aj2, aj3;
  {
    const float* ap = af + (b*256 + j0w + xl)*64;
    aj0 = ap[0]; aj1 = ap[1]; aj2 = ap[3]; aj3 = ap[4];
  }

  __syncthreads();   // w2l/b2w3f/maskF staged

  const f32x4 zero4 = {0.f, 0.f, 0.f, 0.f};
  #pragma unroll 2
  for (int s = 0; s < 4; ++s, j0w += 32) {
    // ---- geom -> B1u g3 octet (k24..28 = rp0,rp1,rv0,rv1,dist) ----
    if (g == 3) {
      #pragma unroll
      for (int n = 0; n < 4; ++n) {
        const float rp0 = aj0 - aic[n][0], rp1 = aj1 - aic[n][1];
        const float rv0 = aj2 - aic[n][2], rv1 = aj3 - aic[n][3];
        const float dist = sqrtf(rp0*rp0 + rp1*rp1);
        u32x4 v;
        v[0] = cvt_pk_bf16(rp0, rp1); v[1] = cvt_pk_bf16(rv0, rv1);
        v[2] = cvt_pk_bf16(dist, 0.f); v[3] = 0u;
        B1u[n] = v;
      }
    }

    // ---- pass 1 (bf16 K=32) + relu -> fp8 pack into pass-2 B-frags ----
    i32x8 Bh1[4];
    #pragma unroll
    for (int m = 0; m < 8; ++m) {
      #pragma unroll
      for (int n = 0; n < 4; ++n) {
        f32x4 a = __builtin_amdgcn_mfma_f32_16x16x32_bf16(Af[m], as_frag(B1u[n]), zero4, 0, 0, 0);
        u32 d = (u32)__builtin_amdgcn_cvt_pk_fp8_f32(fmaxf(a[0], 0.f), fmaxf(a[1], 0.f), 0, false);
        d = (u32)__builtin_amdgcn_cvt_pk_fp8_f32(fmaxf(a[2], 0.f), fmaxf(a[3], 0.f), (int)d, true);
        Bh1[n][m] = (int)d;
      }
    }

    // ---- prefetch next step's v-octets + geom comps (hide under pass2) ----
    if (s < 3) {
      if (g == 1) {
        #pragma unroll
        for (int m = 0; m < 8; ++m)
          Af[m] = *(const s16x8*)(vT + (b*128 + 16*m + x)*256 + j0w + 32);
      }
      const float* ap = af + (b*256 + j0w + 32 + xl)*64;
      aj0 = ap[0]; aj1 = ap[1]; aj2 = ap[3]; aj3 = ap[4];
    }

    // ---- pass 2 (A from LDS, C=b2) + scalar pass-3 epilogue ----
    float ep0 = 0.f, ep1 = 0.f, ep2 = 0.f, ep3 = 0.f;
    __builtin_amdgcn_s_setprio(1);
    #pragma unroll
    for (int w = 0; w < 8; ++w) {
      union { i32x8 v; u32x4 q[2]; } W;
      W.q[0] = *(const u32x4*)(w2l + lanebyte + 2304*w);
      W.q[1] = *(const u32x4*)(w2l + lanebyte + 2304*w + 16);
      const f32x4 b2c = *(const f32x4*)&b2w3f[0][16*w + 4*g];
      const f32x4 w3v = *(const f32x4*)&b2w3f[1][16*w + 4*g];
      f32x4 d0 = __builtin_amdgcn_mfma_scale_f32_16x16x128_f8f6f4(W.v, Bh1[0], b2c, 0, 0, 0, SCALE1, 0, SCALE1);
      f32x4 d1 = __builtin_amdgcn_mfma_scale_f32_16x16x128_f8f6f4(W.v, Bh1[1], b2c, 0, 0, 0, SCALE1, 0, SCALE1);
      f32x4 d2 = __builtin_amdgcn_mfma_scale_f32_16x16x128_f8f6f4(W.v, Bh1[2], b2c, 0, 0, 0, SCALE1, 0, SCALE1);
      f32x4 d3 = __builtin_amdgcn_mfma_scale_f32_16x16x128_f8f6f4(W.v, Bh1[3], b2c, 0, 0, 0, SCALE1, 0, SCALE1);
      #pragma unroll
      for (int r = 0; r < 4; ++r) {
        ep0 += fmaxf(d0[r], 0.f) * w3v[r];
        ep1 += fmaxf(d1[r], 0.f) * w3v[r];
        ep2 += fmaxf(d2[r], 0.f) * w3v[r];
        ep3 += fmaxf(d3[r], 0.f) * w3v[r];
      }
    }
    __builtin_amdgcn_s_setprio(0);
    ep0 += __shfl_xor(ep0, 16); ep0 += __shfl_xor(ep0, 32);
    ep1 += __shfl_xor(ep1, 16); ep1 += __shfl_xor(ep1, 32);
    ep2 += __shfl_xor(ep2, 16); ep2 += __shfl_xor(ep2, 32);
    ep3 += __shfl_xor(ep3, 16); ep3 += __shfl_xor(ep3, 32);

    // lane (x, g) writes pair q = 16g + x: (iloc = 2g+xh, jloc = xl)
    const float es = (g == 0) ? ep0 : (g == 1) ? ep1 : (g == 2) ? ep2 : ep3;
    const int gi = i0 + 2*g + xh, gj = j0w + xl;
    const float e = es + b3v;
    const int off = (b << 16) + (gi << 8) + gj;
    if (mlp == 0) {
      const bool keep = (maskF[gi] * maskF[gj] > 0.5f) && (gi != gj);
      out[off] = keep ? e : 1000000.0f;
    } else {
      e_raw[off] = e;
    }
  }
}

// =====================================================================
// kernel 3: e_none symmetrize + mask (tile-pair, coalesced).
__global__ __launch_bounds__(256) void k_sym(
    const float* __restrict__ e_raw, const float* __restrict__ mask, float* __restrict__ out) {
  const int tp = blockIdx.x, b = blockIdx.y;
  int ti, tj;
  if (tp < 4)      { ti = 0; tj = tp; }
  else if (tp < 7) { ti = 1; tj = tp - 3; }
  else if (tp < 9) { ti = 2; tj = tp - 5; }
  else             { ti = 3; tj = 3; }
  __shared__ float E1[64][65], E2[64][65];
  __shared__ float mI[64], mJ[64];
  const int t = threadIdx.x;
  const int i0 = ti*64, j0 = tj*64, base = b << 16;
  for (int idx = t; idx < 4096; idx += 256) {
    const int r = idx >> 6, c = idx & 63;
    E1[r][c] = e_raw[base + (i0 + r)*256 + j0 + c];
    E2[r][c] = e_raw[base + (j0 + r)*256 + i0 + c];
  }
  if (t < 64)       mI[t] = mask[b*256 + i0 + t];
  else if (t < 128) mJ[t-64] = mask[b*256 + j0 + (t-64)];
  __syncthreads();
  for (int idx = t; idx < 4096; idx += 256) {
    const int r = idx >> 6, c = idx & 63;
    const int i = i0 + r, j = j0 + c;
    float v = 1000000.0f;
    if ((mI[r]*mJ[c] > 0.5f) && (i != j)) v = 0.5f*(E1[r][c] + E2[c][r]);
    out[524288 + base + i*256 + j] = v;
  }
  if (ti != tj) {
    for (int idx = t; idx < 4096; idx += 256) {
      const int r = idx >> 6, c = idx & 63;
      float v = 1000000.0f;
      if (mJ[r]*mI[c] > 0.5f) v = 0.5f*(E2[r][c] + E1[c][r]);
      out[524288 + base + (j0 + r)*256 + i0 + c] = v;
    }
  }
}

extern "C" void kernel_launch(void* const* d_in, const int* in_sizes, int n_in,
                              void* d_out, int out_size, void* d_ws, size_t ws_size,
                              hipStream_t stream) {
  const float* af   = (const float*)d_in[0];
  const float* zm   = (const float*)d_in[1];
  const float* zlv  = (const float*)d_in[2];
  const float* mask = (const float*)d_in[3];
  const float* W1d  = (const float*)d_in[4];
  const float* b1d  = (const float*)d_in[5];
  const float* W2d  = (const float*)d_in[6];
  const float* b2d  = (const float*)d_in[7];
  const float* W3d  = (const float*)d_in[8];
  const float* b3d  = (const float*)d_in[9];
  const float* W1n  = (const float*)d_in[10];
  const float* b1n  = (const float*)d_in[11];
  const float* W2n  = (const float*)d_in[12];
  const float* b2n  = (const float*)d_in[13];
  const float* W3n  = (const float*)d_in[14];
  const float* b3n  = (const float*)d_in[15];

  u16*   ws16  = (u16*)d_ws;
  float* e_raw = (float*)((char*)d_ws + ERAW);
  float* out   = (float*)d_out;

  k_uvw<<<dim3(129, 2), 256, 0, stream>>>(af, zm, zlv, W1d, b1d, W1n, b1n, W2d, W2n, ws16);
  k_main<<<dim3(32, 4, 8), 256, 0, stream>>>(af, mask, W1d, b2d, W3d, b3d,
                                             W1n, b2n, W3n, b3n, ws16, e_raw, out);
  k_sym<<<dim3(10, 8), 256, 0, stream>>>(e_raw, mask, out);
}

// Round 13
// 76.569 us; speedup vs baseline: 1.7633x; 1.7633x over previous
//
#include <hip/hip_runtime.h>

typedef unsigned short u16;
typedef unsigned int u32;
typedef short s16x8 __attribute__((ext_vector_type(8)));
typedef float f32x4 __attribute__((ext_vector_type(4)));
typedef u32 u32x4 __attribute__((ext_vector_type(4)));
typedef int i32x8 __attribute__((ext_vector_type(8)));

// ---- workspace byte offsets ----
// uT/vT: [b][h][k] bf16 (u includes b1); W2F8: sigma'-permuted W2^T fp8; e_raw f32
#define UT_D   0u
#define VT_D   524288u
#define UT_N   1048576u
#define VT_N   1572864u
#define W2F8_D 2097152u
#define W2F8_N 2113536u
#define ERAW   2162688u

#define SCALE1 0x7F7F7F7F   // E8M0 = 127 in every byte -> scale factor 1.0

__device__ __forceinline__ u16 f2bf(float x) {
  u32 u = __float_as_uint(x);
  return (u16)((u + 0x7FFFu + ((u >> 16) & 1u)) >> 16);   // RNE
}
__device__ __forceinline__ u32 cvt_pk_bf16(float lo, float hi) {
  u32 r;
  asm("v_cvt_pk_bf16_f32 %0, %1, %2" : "=v"(r) : "v"(lo), "v"(hi));
  return r;
}
__device__ __forceinline__ s16x8 as_frag(u32x4 v) { return __builtin_bit_cast(s16x8, v); }

// =====================================================================
// kernel 1 (merged): blocks x<128: per-agent layer-1 projections, 16 agents
// per block (W1 L2 traffic halved vs 8-agent). block x==128: fp8 W2^T staging.
// sigma': k = 32g + 4m + r  <->  h = 16m + 4g + r
__global__ __launch_bounds__(256) void k_uvw(
    const float* __restrict__ af, const float* __restrict__ zm, const float* __restrict__ zlv,
    const float* __restrict__ W1d, const float* __restrict__ b1d,
    const float* __restrict__ W1n, const float* __restrict__ b1n,
    const float* __restrict__ W2d, const float* __restrict__ W2n,
    u16* __restrict__ ws16) {
  const int mlp = blockIdx.y;
  const int t   = threadIdx.x;
  if (blockIdx.x == 128) {
    const float* W2 = mlp ? W2n : W2d;
    u16* W2s8 = (u16*)((char*)ws16 + (mlp ? W2F8_N : W2F8_D));   // [nn][k] fp8, u16 pairs
    for (int idx = t; idx < 8192; idx += 256) {
      const int nn = idx >> 6, k2 = idx & 63, k = 2*k2;
      const int g = k >> 5, m = (k >> 2) & 7, r = k & 3;
      const int h0 = 16*m + 4*g + r;
      const u32 pk = (u32)__builtin_amdgcn_cvt_pk_fp8_f32(W2[h0*128 + nn], W2[(h0+1)*128 + nn], 0, false);
      W2s8[nn*64 + k2] = (u16)(pk & 0xFFFFu);
    }
    return;
  }
  const int a0 = blockIdx.x * 16;
  __shared__ float xs[16][128];
  for (int idx = t; idx < 2048; idx += 256) {
    const int a = idx >> 7, f = idx & 127, ga = a0 + a;
    float v;
    if (f < 64)      v = af[ga*64 + f];
    else if (f < 96) v = zm[ga*32 + (f-64)];
    else             v = zlv[ga*32 + (f-96)];
    xs[a][f] = v;
  }
  __syncthreads();
  const int h = t & 127, half = t >> 7;
  const float* W1 = mlp ? W1n : W1d;
  const int aoff = (mlp ? 5 : 0) + 64*half;
  const int zoff = 69 + 64*half;
  float acc[16];
  #pragma unroll
  for (int a = 0; a < 16; ++a) acc[a] = 0.f;
  #pragma unroll 2
  for (int f = 0; f < 64; f += 4) {
    const float w0 = W1[(aoff+f  )*128 + h];
    const float w1 = W1[(aoff+f+1)*128 + h];
    const float w2 = W1[(aoff+f+2)*128 + h];
    const float w3 = W1[(aoff+f+3)*128 + h];
    #pragma unroll
    for (int a = 0; a < 16; ++a) {
      const f32x4 xv = *(const f32x4*)&xs[a][f];
      acc[a] = fmaf(xv[3], w3, fmaf(xv[2], w2, fmaf(xv[1], w1, fmaf(xv[0], w0, acc[a]))));
    }
  }
  #pragma unroll 2
  for (int f = 64; f < 128; f += 4) {
    const float w0 = W1[(zoff+f  )*128 + h];
    const float w1 = W1[(zoff+f+1)*128 + h];
    const float w2 = W1[(zoff+f+2)*128 + h];
    const float w3 = W1[(zoff+f+3)*128 + h];
    #pragma unroll
    for (int a = 0; a < 16; ++a) {
      const f32x4 xv = *(const f32x4*)&xs[a][f];
      acc[a] = fmaf(xv[3], w3, fmaf(xv[2], w2, fmaf(xv[1], w1, fmaf(xv[0], w0, acc[a]))));
    }
  }
  const float bb = half ? 0.f : (mlp ? b1n[h] : b1d[h]);
  u16 pk[16];
  #pragma unroll
  for (int a = 0; a < 16; ++a) pk[a] = f2bf(acc[a] + bb);
  const int b = a0 >> 8;
  u16* dT = (u16*)((char*)ws16 + (mlp ? (half ? VT_N : UT_N) : (half ? VT_D : UT_D)));
  *(s16x8*)(dT + (b*128 + h)*256 + (a0 & 255))     = *(s16x8*)&pk[0];
  *(s16x8*)(dT + (b*128 + h)*256 + (a0 & 255) + 8) = *(s16x8*)&pk[8];
}

// =====================================================================
// kernel 2: main == R10's validated schedule (unroll 1 -- unroll 2 spilled
// in R12; >2 blocks/CU spilled in R6/R11: register sweet spot is exactly
// this shape). ONE launch change: 8 steps/block, 512 blocks = 2/CU x 1
// round -- W2-LDS staging paid once, no second-round ramp, zero tail.
__global__ __launch_bounds__(256, 2) void k_main(
    const float* __restrict__ af, const float* __restrict__ mask,
    const float* __restrict__ W1d, const float* __restrict__ b2d, const float* __restrict__ W3d, const float* __restrict__ b3d,
    const float* __restrict__ W1n, const float* __restrict__ b2n, const float* __restrict__ W3n, const float* __restrict__ b3n,
    const u16* __restrict__ ws16, float* __restrict__ e_raw, float* __restrict__ out) {
  const int t   = threadIdx.x;
  const int i0  = blockIdx.x * 8;
  const int mlp = blockIdx.y & 1;
  const int b   = blockIdx.z;

  __shared__ char  w2l[128*144];   // fp8 W2 sigma', rows padded to 144 B (16 | 144)
  __shared__ float b2w3f[2][128];
  __shared__ float maskF[256];

  // stage W2 fp8 into padded LDS (linear global -> 144B-stride rows)
  {
    const char* w2g = (const char*)ws16 + (mlp ? W2F8_N : W2F8_D);
    const int row = t >> 1, c0 = (t & 1) * 64;
    #pragma unroll
    for (int q = 0; q < 4; ++q) {
      u32x4 v = *(const u32x4*)(w2g + row*128 + c0 + 16*q);
      *(u32x4*)(w2l + row*144 + c0 + 16*q) = v;
    }
  }
  if (t < 128) b2w3f[0][t] = (mlp ? b2n : b2d)[t];
  else         b2w3f[1][t-128] = (mlp ? W3n : W3d)[t-128];
  maskF[t] = mask[b*256 + t];
  const float b3v = (mlp ? b3n : b3d)[0];

  const int wv = t >> 6, l = t & 63, x = l & 15, g = l >> 4;
  const int xh = x >> 3, xl = x & 7;
  const int lanebyte = 144*x + 32*g;   // 16B-aligned for all lanes; +2304*w per tile

  const u16* uT = (const u16*)((const char*)ws16 + (mlp ? UT_N : UT_D));
  const u16* vT = (const u16*)((const char*)ws16 + (mlp ? VT_N : VT_D));
  const float* W1 = mlp ? W1n : W1d;
  const int grow = mlp ? 0 : 128;

  // ---- persistent pass-1 A-frags: g0 = u'_i octet, g1 = v_j (per step),
  //      g2 = 0, g3 = Wg octet ----
  s16x8 Af[8];
  #pragma unroll
  for (int m = 0; m < 8; ++m) {
    u32x4 a = {0u, 0u, 0u, 0u};
    if (g == 0) {
      a = *(const u32x4*)(uT + (b*128 + 16*m + x)*256 + i0);
    } else if (g == 3) {
      const int h = 16*m + x;
      const float w0 = W1[(grow+0)*128 + h], w1 = W1[(grow+1)*128 + h];
      const float w2 = W1[(grow+2)*128 + h], w3 = W1[(grow+3)*128 + h];
      const float w4 = W1[(grow+4)*128 + h];
      a[0] = cvt_pk_bf16(w0, w1); a[1] = cvt_pk_bf16(w2, w3);
      a[2] = cvt_pk_bf16(w4, 0.f); a[3] = 0u;
    }
    Af[m] = __builtin_bit_cast(s16x8, a);
  }

  // ---- static one-hot B-frags (g0: i-onehot, g1: j-onehot); g3 geom/step ----
  u32x4 B1u[4];
  #pragma unroll
  for (int n = 0; n < 4; ++n) {
    u32x4 v = {0u, 0u, 0u, 0u};
    if (g == 0) {
      const int il = 2*n + xh;
      v[il >> 1] = (il & 1) ? 0x3F800000u : 0x3F80u;
    } else if (g == 1) {
      v[xl >> 1] = (xl & 1) ? 0x3F800000u : 0x3F80u;
    }
    B1u[n] = v;
  }

  // ---- i-side geom comps (block-static): 0,1,3,4 of i = i0+2n+xh ----
  f32x4 aic[4];
  #pragma unroll
  for (int n = 0; n < 4; ++n) {
    const float* ap = af + (b*256 + i0 + 2*n + xh)*64;
    aic[n][0] = ap[0]; aic[n][1] = ap[1]; aic[n][2] = ap[3]; aic[n][3] = ap[4];
  }

  int j0w = wv*8;
  if (g == 1) {
    #pragma unroll
    for (int m = 0; m < 8; ++m)
      Af[m] = *(const s16x8*)(vT + (b*128 + 16*m + x)*256 + j0w);
  }
  float aj0, aj1, aj2, aj3;
  {
    const float* ap = af + (b*256 + j0w + xl)*64;
    aj0 = ap[0]; aj1 = ap[1]; aj2 = ap[3]; aj3 = ap[4];
  }

  __syncthreads();   // w2l/b2w3f/maskF staged

  const f32x4 zero4 = {0.f, 0.f, 0.f, 0.f};
  #pragma unroll 1
  for (int s = 0; s < 8; ++s, j0w += 32) {
    // ---- geom -> B1u g3 octet (k24..28 = rp0,rp1,rv0,rv1,dist) ----
    if (g == 3) {
      #pragma unroll
      for (int n = 0; n < 4; ++n) {
        const float rp0 = aj0 - aic[n][0], rp1 = aj1 - aic[n][1];
        const float rv0 = aj2 - aic[n][2], rv1 = aj3 - aic[n][3];
        const float dist = sqrtf(rp0*rp0 + rp1*rp1);
        u32x4 v;
        v[0] = cvt_pk_bf16(rp0, rp1); v[1] = cvt_pk_bf16(rv0, rv1);
        v[2] = cvt_pk_bf16(dist, 0.f); v[3] = 0u;
        B1u[n] = v;
      }
    }

    // ---- pass 1 (bf16 K=32) + relu -> fp8 pack into pass-2 B-frags ----
    i32x8 Bh1[4];
    #pragma unroll
    for (int m = 0; m < 8; ++m) {
      #pragma unroll
      for (int n = 0; n < 4; ++n) {
        f32x4 a = __builtin_amdgcn_mfma_f32_16x16x32_bf16(Af[m], as_frag(B1u[n]), zero4, 0, 0, 0);
        u32 d = (u32)__builtin_amdgcn_cvt_pk_fp8_f32(fmaxf(a[0], 0.f), fmaxf(a[1], 0.f), 0, false);
        d = (u32)__builtin_amdgcn_cvt_pk_fp8_f32(fmaxf(a[2], 0.f), fmaxf(a[3], 0.f), (int)d, true);
        Bh1[n][m] = (int)d;
      }
    }

    // ---- prefetch next step's v-octets + geom comps (hide under pass2) ----
    if (s < 7) {
      if (g == 1) {
        #pragma unroll
        for (int m = 0; m < 8; ++m)
          Af[m] = *(const s16x8*)(vT + (b*128 + 16*m + x)*256 + j0w + 32);
      }
      const float* ap = af + (b*256 + j0w + 32 + xl)*64;
      aj0 = ap[0]; aj1 = ap[1]; aj2 = ap[3]; aj3 = ap[4];
    }

    // ---- pass 2 (A from LDS, C=b2) + scalar pass-3 epilogue ----
    float ep0 = 0.f, ep1 = 0.f, ep2 = 0.f, ep3 = 0.f;
    __builtin_amdgcn_s_setprio(1);
    #pragma unroll
    for (int w = 0; w < 8; ++w) {
      union { i32x8 v; u32x4 q[2]; } W;
      W.q[0] = *(const u32x4*)(w2l + lanebyte + 2304*w);
      W.q[1] = *(const u32x4*)(w2l + lanebyte + 2304*w + 16);
      const f32x4 b2c = *(const f32x4*)&b2w3f[0][16*w + 4*g];
      const f32x4 w3v = *(const f32x4*)&b2w3f[1][16*w + 4*g];
      f32x4 d0 = __builtin_amdgcn_mfma_scale_f32_16x16x128_f8f6f4(W.v, Bh1[0], b2c, 0, 0, 0, SCALE1, 0, SCALE1);
      f32x4 d1 = __builtin_amdgcn_mfma_scale_f32_16x16x128_f8f6f4(W.v, Bh1[1], b2c, 0, 0, 0, SCALE1, 0, SCALE1);
      f32x4 d2 = __builtin_amdgcn_mfma_scale_f32_16x16x128_f8f6f4(W.v, Bh1[2], b2c, 0, 0, 0, SCALE1, 0, SCALE1);
      f32x4 d3 = __builtin_amdgcn_mfma_scale_f32_16x16x128_f8f6f4(W.v, Bh1[3], b2c, 0, 0, 0, SCALE1, 0, SCALE1);
      #pragma unroll
      for (int r = 0; r < 4; ++r) {
        ep0 += fmaxf(d0[r], 0.f) * w3v[r];
        ep1 += fmaxf(d1[r], 0.f) * w3v[r];
        ep2 += fmaxf(d2[r], 0.f) * w3v[r];
        ep3 += fmaxf(d3[r], 0.f) * w3v[r];
      }
    }
    __builtin_amdgcn_s_setprio(0);
    ep0 += __shfl_xor(ep0, 16); ep0 += __shfl_xor(ep0, 32);
    ep1 += __shfl_xor(ep1, 16); ep1 += __shfl_xor(ep1, 32);
    ep2 += __shfl_xor(ep2, 16); ep2 += __shfl_xor(ep2, 32);
    ep3 += __shfl_xor(ep3, 16); ep3 += __shfl_xor(ep3, 32);

    // lane (x, g) writes pair q = 16g + x: (iloc = 2g+xh, jloc = xl)
    const float es = (g == 0) ? ep0 : (g == 1) ? ep1 : (g == 2) ? ep2 : ep3;
    const int gi = i0 + 2*g + xh, gj = j0w + xl;
    const float e = es + b3v;
    const int off = (b << 16) + (gi << 8) + gj;
    if (mlp == 0) {
      const bool keep = (maskF[gi] * maskF[gj] > 0.5f) && (gi != gj);
      out[off] = keep ? e : 1000000.0f;
    } else {
      e_raw[off] = e;
    }
  }
}

// =====================================================================
// kernel 3: e_none symmetrize + mask (tile-pair, coalesced).
__global__ __launch_bounds__(256) void k_sym(
    const float* __restrict__ e_raw, const float* __restrict__ mask, float* __restrict__ out) {
  const int tp = blockIdx.x, b = blockIdx.y;
  int ti, tj;
  if (tp < 4)      { ti = 0; tj = tp; }
  else if (tp < 7) { ti = 1; tj = tp - 3; }
  else if (tp < 9) { ti = 2; tj = tp - 5; }
  else             { ti = 3; tj = 3; }
  __shared__ float E1[64][65], E2[64][65];
  __shared__ float mI[64], mJ[64];
  const int t = threadIdx.x;
  const int i0 = ti*64, j0 = tj*64, base = b << 16;
  for (int idx = t; idx < 4096; idx += 256) {
    const int r = idx >> 6, c = idx & 63;
    E1[r][c] = e_raw[base + (i0 + r)*256 + j0 + c];
    E2[r][c] = e_raw[base + (j0 + r)*256 + i0 + c];
  }
  if (t < 64)       mI[t] = mask[b*256 + i0 + t];
  else if (t < 128) mJ[t-64] = mask[b*256 + j0 + (t-64)];
  __syncthreads();
  for (int idx = t; idx < 4096; idx += 256) {
    const int r = idx >> 6, c = idx & 63;
    const int i = i0 + r, j = j0 + c;
    float v = 1000000.0f;
    if ((mI[r]*mJ[c] > 0.5f) && (i != j)) v = 0.5f*(E1[r][c] + E2[c][r]);
    out[524288 + base + i*256 + j] = v;
  }
  if (ti != tj) {
    for (int idx = t; idx < 4096; idx += 256) {
      const int r = idx >> 6, c = idx & 63;
      float v = 1000000.0f;
      if (mJ[r]*mI[c] > 0.5f) v = 0.5f*(E2[r][c] + E1[c][r]);
      out[524288 + base + (j0 + r)*256 + i0 + c] = v;
    }
  }
}

extern "C" void kernel_launch(void* const* d_in, const int* in_sizes, int n_in,
                              void* d_out, int out_size, void* d_ws, size_t ws_size,
                              hipStream_t stream) {
  const float* af   = (const float*)d_in[0];
  const float* zm   = (const float*)d_in[1];
  const float* zlv  = (const float*)d_in[2];
  const float* mask = (const float*)d_in[3];
  const float* W1d  = (const float*)d_in[4];
  const float* b1d  = (const float*)d_in[5];
  const float* W2d  = (const float*)d_in[6];
  const float* b2d  = (const float*)d_in[7];
  const float* W3d  = (const float*)d_in[8];
  const float* b3d  = (const float*)d_in[9];
  const float* W1n  = (const float*)d_in[10];
  const float* b1n  = (const float*)d_in[11];
  const float* W2n  = (const float*)d_in[12];
  const float* b2n  = (const float*)d_in[13];
  const float* W3n  = (const float*)d_in[14];
  const float* b3n  = (const float*)d_in[15];

  u16*   ws16  = (u16*)d_ws;
  float* e_raw = (float*)((char*)d_ws + ERAW);
  float* out   = (float*)d_out;

  k_uvw<<<dim3(129, 2), 256, 0, stream>>>(af, zm, zlv, W1d, b1d, W1n, b1n, W2d, W2n, ws16);
  k_main<<<dim3(32, 2, 8), 256, 0, stream>>>(af, mask, W1d, b2d, W3d, b3d,
                                             W1n, b2n, W3n, b3n, ws16, e_raw, out);
  k_sym<<<dim3(10, 8), 256, 0, stream>>>(e_raw, mask, out);
}

// Round 14
// 67.952 us; speedup vs baseline: 1.9869x; 1.1268x over previous
//
#include <hip/hip_runtime.h>

typedef unsigned short u16;
typedef unsigned int u32;
typedef short s16x8 __attribute__((ext_vector_type(8)));
typedef float f32x4 __attribute__((ext_vector_type(4)));
typedef u32 u32x4 __attribute__((ext_vector_type(4)));
typedef int i32x8 __attribute__((ext_vector_type(8)));

// ---- workspace byte offsets ----
// uT/vT: [b][h][k] bf16 (u includes b1); W2F8: sigma'-permuted W2^T fp8; e_raw f32
#define UT_D   0u
#define VT_D   524288u
#define UT_N   1048576u
#define VT_N   1572864u
#define W2F8_D 2097152u
#define W2F8_N 2113536u
#define ERAW   2162688u

#define SCALE1 0x7F7F7F7F   // E8M0 = 127 in every byte -> scale factor 1.0

__device__ __forceinline__ u16 f2bf(float x) {
  u32 u = __float_as_uint(x);
  return (u16)((u + 0x7FFFu + ((u >> 16) & 1u)) >> 16);   // RNE
}
__device__ __forceinline__ u32 cvt_pk_bf16(float lo, float hi) {
  u32 r;
  asm("v_cvt_pk_bf16_f32 %0, %1, %2" : "=v"(r) : "v"(lo), "v"(hi));
  return r;
}
__device__ __forceinline__ s16x8 as_frag(u32x4 v) { return __builtin_bit_cast(s16x8, v); }

// =====================================================================
// kernel 1 (merged): blocks x<256: per-agent layer-1 projections, 8 agents
// per block (R10-validated: 514 blocks = good TLP; 16-agent regressed in
// R13 to ~1 block/CU). block x==256: sigma'-permuted fp8 W2^T staging.
// sigma': k = 32g + 4m + r  <->  h = 16m + 4g + r
__global__ __launch_bounds__(256) void k_uvw(
    const float* __restrict__ af, const float* __restrict__ zm, const float* __restrict__ zlv,
    const float* __restrict__ W1d, const float* __restrict__ b1d,
    const float* __restrict__ W1n, const float* __restrict__ b1n,
    const float* __restrict__ W2d, const float* __restrict__ W2n,
    u16* __restrict__ ws16) {
  const int mlp = blockIdx.y;
  const int t   = threadIdx.x;
  if (blockIdx.x == 256) {
    const float* W2 = mlp ? W2n : W2d;
    u16* W2s8 = (u16*)((char*)ws16 + (mlp ? W2F8_N : W2F8_D));   // [nn][k] fp8, u16 pairs
    for (int idx = t; idx < 8192; idx += 256) {
      const int nn = idx >> 6, k2 = idx & 63, k = 2*k2;
      const int g = k >> 5, m = (k >> 2) & 7, r = k & 3;
      const int h0 = 16*m + 4*g + r;
      const u32 pk = (u32)__builtin_amdgcn_cvt_pk_fp8_f32(W2[h0*128 + nn], W2[(h0+1)*128 + nn], 0, false);
      W2s8[nn*64 + k2] = (u16)(pk & 0xFFFFu);
    }
    return;
  }
  const int a0 = blockIdx.x * 8;
  __shared__ float xs[8][128];
  for (int idx = t; idx < 1024; idx += 256) {
    const int a = idx >> 7, f = idx & 127, ga = a0 + a;
    float v;
    if (f < 64)      v = af[ga*64 + f];
    else if (f < 96) v = zm[ga*32 + (f-64)];
    else             v = zlv[ga*32 + (f-96)];
    xs[a][f] = v;
  }
  __syncthreads();
  const int h = t & 127, half = t >> 7;
  const float* W1 = mlp ? W1n : W1d;
  const int aoff = (mlp ? 5 : 0) + 64*half;
  const int zoff = 69 + 64*half;
  float acc[8];
  #pragma unroll
  for (int a = 0; a < 8; ++a) acc[a] = 0.f;
  #pragma unroll 2
  for (int f = 0; f < 64; f += 4) {
    const float w0 = W1[(aoff+f  )*128 + h];
    const float w1 = W1[(aoff+f+1)*128 + h];
    const float w2 = W1[(aoff+f+2)*128 + h];
    const float w3 = W1[(aoff+f+3)*128 + h];
    #pragma unroll
    for (int a = 0; a < 8; ++a) {
      const f32x4 xv = *(const f32x4*)&xs[a][f];
      acc[a] = fmaf(xv[3], w3, fmaf(xv[2], w2, fmaf(xv[1], w1, fmaf(xv[0], w0, acc[a]))));
    }
  }
  #pragma unroll 2
  for (int f = 64; f < 128; f += 4) {
    const float w0 = W1[(zoff+f  )*128 + h];
    const float w1 = W1[(zoff+f+1)*128 + h];
    const float w2 = W1[(zoff+f+2)*128 + h];
    const float w3 = W1[(zoff+f+3)*128 + h];
    #pragma unroll
    for (int a = 0; a < 8; ++a) {
      const f32x4 xv = *(const f32x4*)&xs[a][f];
      acc[a] = fmaf(xv[3], w3, fmaf(xv[2], w2, fmaf(xv[1], w1, fmaf(xv[0], w0, acc[a]))));
    }
  }
  const float bb = half ? 0.f : (mlp ? b1n[h] : b1d[h]);
  u16 pk[8];
  #pragma unroll
  for (int a = 0; a < 8; ++a) pk[a] = f2bf(acc[a] + bb);
  const int b = a0 >> 8;
  u16* dT = (u16*)((char*)ws16 + (mlp ? (half ? VT_N : UT_N) : (half ? VT_D : UT_D)));
  *(s16x8*)(dT + (b*128 + h)*256 + (a0 & 255)) = *(s16x8*)pk;
}

// =====================================================================
// kernel 2: main == R13 (validated 54.9us, absmax 0.0215): R10's schedule
// (unroll 1; unroll-2 / >2 blocks-per-CU all spill -- R6/R11/R12) with the
// single-round launch: 8 steps/block, 512 blocks = 2/CU x exactly 1 round.
__global__ __launch_bounds__(256, 2) void k_main(
    const float* __restrict__ af, const float* __restrict__ mask,
    const float* __restrict__ W1d, const float* __restrict__ b2d, const float* __restrict__ W3d, const float* __restrict__ b3d,
    const float* __restrict__ W1n, const float* __restrict__ b2n, const float* __restrict__ W3n, const float* __restrict__ b3n,
    const u16* __restrict__ ws16, float* __restrict__ e_raw, float* __restrict__ out) {
  const int t   = threadIdx.x;
  const int i0  = blockIdx.x * 8;
  const int mlp = blockIdx.y & 1;
  const int b   = blockIdx.z;

  __shared__ char  w2l[128*144];   // fp8 W2 sigma', rows padded to 144 B (16 | 144)
  __shared__ float b2w3f[2][128];
  __shared__ float maskF[256];

  // stage W2 fp8 into padded LDS (linear global -> 144B-stride rows)
  {
    const char* w2g = (const char*)ws16 + (mlp ? W2F8_N : W2F8_D);
    const int row = t >> 1, c0 = (t & 1) * 64;
    #pragma unroll
    for (int q = 0; q < 4; ++q) {
      u32x4 v = *(const u32x4*)(w2g + row*128 + c0 + 16*q);
      *(u32x4*)(w2l + row*144 + c0 + 16*q) = v;
    }
  }
  if (t < 128) b2w3f[0][t] = (mlp ? b2n : b2d)[t];
  else         b2w3f[1][t-128] = (mlp ? W3n : W3d)[t-128];
  maskF[t] = mask[b*256 + t];
  const float b3v = (mlp ? b3n : b3d)[0];

  const int wv = t >> 6, l = t & 63, x = l & 15, g = l >> 4;
  const int xh = x >> 3, xl = x & 7;
  const int lanebyte = 144*x + 32*g;   // 16B-aligned for all lanes; +2304*w per tile

  const u16* uT = (const u16*)((const char*)ws16 + (mlp ? UT_N : UT_D));
  const u16* vT = (const u16*)((const char*)ws16 + (mlp ? VT_N : VT_D));
  const float* W1 = mlp ? W1n : W1d;
  const int grow = mlp ? 0 : 128;

  // ---- persistent pass-1 A-frags: g0 = u'_i octet, g1 = v_j (per step),
  //      g2 = 0, g3 = Wg octet ----
  s16x8 Af[8];
  #pragma unroll
  for (int m = 0; m < 8; ++m) {
    u32x4 a = {0u, 0u, 0u, 0u};
    if (g == 0) {
      a = *(const u32x4*)(uT + (b*128 + 16*m + x)*256 + i0);
    } else if (g == 3) {
      const int h = 16*m + x;
      const float w0 = W1[(grow+0)*128 + h], w1 = W1[(grow+1)*128 + h];
      const float w2 = W1[(grow+2)*128 + h], w3 = W1[(grow+3)*128 + h];
      const float w4 = W1[(grow+4)*128 + h];
      a[0] = cvt_pk_bf16(w0, w1); a[1] = cvt_pk_bf16(w2, w3);
      a[2] = cvt_pk_bf16(w4, 0.f); a[3] = 0u;
    }
    Af[m] = __builtin_bit_cast(s16x8, a);
  }

  // ---- static one-hot B-frags (g0: i-onehot, g1: j-onehot); g3 geom/step ----
  u32x4 B1u[4];
  #pragma unroll
  for (int n = 0; n < 4; ++n) {
    u32x4 v = {0u, 0u, 0u, 0u};
    if (g == 0) {
      const int il = 2*n + xh;
      v[il >> 1] = (il & 1) ? 0x3F800000u : 0x3F80u;
    } else if (g == 1) {
      v[xl >> 1] = (xl & 1) ? 0x3F800000u : 0x3F80u;
    }
    B1u[n] = v;
  }

  // ---- i-side geom comps (block-static): 0,1,3,4 of i = i0+2n+xh ----
  f32x4 aic[4];
  #pragma unroll
  for (int n = 0; n < 4; ++n) {
    const float* ap = af + (b*256 + i0 + 2*n + xh)*64;
    aic[n][0] = ap[0]; aic[n][1] = ap[1]; aic[n][2] = ap[3]; aic[n][3] = ap[4];
  }

  int j0w = wv*8;
  if (g == 1) {
    #pragma unroll
    for (int m = 0; m < 8; ++m)
      Af[m] = *(const s16x8*)(vT + (b*128 + 16*m + x)*256 + j0w);
  }
  float aj0, aj1, aj2, aj3;
  {
    const float* ap = af + (b*256 + j0w + xl)*64;
    aj0 = ap[0]; aj1 = ap[1]; aj2 = ap[3]; aj3 = ap[4];
  }

  __syncthreads();   // w2l/b2w3f/maskF staged

  const f32x4 zero4 = {0.f, 0.f, 0.f, 0.f};
  #pragma unroll 1
  for (int s = 0; s < 8; ++s, j0w += 32) {
    // ---- geom -> B1u g3 octet (k24..28 = rp0,rp1,rv0,rv1,dist) ----
    if (g == 3) {
      #pragma unroll
      for (int n = 0; n < 4; ++n) {
        const float rp0 = aj0 - aic[n][0], rp1 = aj1 - aic[n][1];
        const float rv0 = aj2 - aic[n][2], rv1 = aj3 - aic[n][3];
        const float dist = sqrtf(rp0*rp0 + rp1*rp1);
        u32x4 v;
        v[0] = cvt_pk_bf16(rp0, rp1); v[1] = cvt_pk_bf16(rv0, rv1);
        v[2] = cvt_pk_bf16(dist, 0.f); v[3] = 0u;
        B1u[n] = v;
      }
    }

    // ---- pass 1 (bf16 K=32) + relu -> fp8 pack into pass-2 B-frags ----
    i32x8 Bh1[4];
    #pragma unroll
    for (int m = 0; m < 8; ++m) {
      #pragma unroll
      for (int n = 0; n < 4; ++n) {
        f32x4 a = __builtin_amdgcn_mfma_f32_16x16x32_bf16(Af[m], as_frag(B1u[n]), zero4, 0, 0, 0);
        u32 d = (u32)__builtin_amdgcn_cvt_pk_fp8_f32(fmaxf(a[0], 0.f), fmaxf(a[1], 0.f), 0, false);
        d = (u32)__builtin_amdgcn_cvt_pk_fp8_f32(fmaxf(a[2], 0.f), fmaxf(a[3], 0.f), (int)d, true);
        Bh1[n][m] = (int)d;
      }
    }

    // ---- prefetch next step's v-octets + geom comps (hide under pass2) ----
    if (s < 7) {
      if (g == 1) {
        #pragma unroll
        for (int m = 0; m < 8; ++m)
          Af[m] = *(const s16x8*)(vT + (b*128 + 16*m + x)*256 + j0w + 32);
      }
      const float* ap = af + (b*256 + j0w + 32 + xl)*64;
      aj0 = ap[0]; aj1 = ap[1]; aj2 = ap[3]; aj3 = ap[4];
    }

    // ---- pass 2 (A from LDS, C=b2) + scalar pass-3 epilogue ----
    float ep0 = 0.f, ep1 = 0.f, ep2 = 0.f, ep3 = 0.f;
    __builtin_amdgcn_s_setprio(1);
    #pragma unroll
    for (int w = 0; w < 8; ++w) {
      union { i32x8 v; u32x4 q[2]; } W;
      W.q[0] = *(const u32x4*)(w2l + lanebyte + 2304*w);
      W.q[1] = *(const u32x4*)(w2l + lanebyte + 2304*w + 16);
      const f32x4 b2c = *(const f32x4*)&b2w3f[0][16*w + 4*g];
      const f32x4 w3v = *(const f32x4*)&b2w3f[1][16*w + 4*g];
      f32x4 d0 = __builtin_amdgcn_mfma_scale_f32_16x16x128_f8f6f4(W.v, Bh1[0], b2c, 0, 0, 0, SCALE1, 0, SCALE1);
      f32x4 d1 = __builtin_amdgcn_mfma_scale_f32_16x16x128_f8f6f4(W.v, Bh1[1], b2c, 0, 0, 0, SCALE1, 0, SCALE1);
      f32x4 d2 = __builtin_amdgcn_mfma_scale_f32_16x16x128_f8f6f4(W.v, Bh1[2], b2c, 0, 0, 0, SCALE1, 0, SCALE1);
      f32x4 d3 = __builtin_amdgcn_mfma_scale_f32_16x16x128_f8f6f4(W.v, Bh1[3], b2c, 0, 0, 0, SCALE1, 0, SCALE1);
      #pragma unroll
      for (int r = 0; r < 4; ++r) {
        ep0 += fmaxf(d0[r], 0.f) * w3v[r];
        ep1 += fmaxf(d1[r], 0.f) * w3v[r];
        ep2 += fmaxf(d2[r], 0.f) * w3v[r];
        ep3 += fmaxf(d3[r], 0.f) * w3v[r];
      }
    }
    __builtin_amdgcn_s_setprio(0);
    ep0 += __shfl_xor(ep0, 16); ep0 += __shfl_xor(ep0, 32);
    ep1 += __shfl_xor(ep1, 16); ep1 += __shfl_xor(ep1, 32);
    ep2 += __shfl_xor(ep2, 16); ep2 += __shfl_xor(ep2, 32);
    ep3 += __shfl_xor(ep3, 16); ep3 += __shfl_xor(ep3, 32);

    // lane (x, g) writes pair q = 16g + x: (iloc = 2g+xh, jloc = xl)
    const float es = (g == 0) ? ep0 : (g == 1) ? ep1 : (g == 2) ? ep2 : ep3;
    const int gi = i0 + 2*g + xh, gj = j0w + xl;
    const float e = es + b3v;
    const int off = (b << 16) + (gi << 8) + gj;
    if (mlp == 0) {
      const bool keep = (maskF[gi] * maskF[gj] > 0.5f) && (gi != gj);
      out[off] = keep ? e : 1000000.0f;
    } else {
      e_raw[off] = e;
    }
  }
}

// =====================================================================
// kernel 3: e_none symmetrize + mask (tile-pair, coalesced).
__global__ __launch_bounds__(256) void k_sym(
    const float* __restrict__ e_raw, const float* __restrict__ mask, float* __restrict__ out) {
  const int tp = blockIdx.x, b = blockIdx.y;
  int ti, tj;
  if (tp < 4)      { ti = 0; tj = tp; }
  else if (tp < 7) { ti = 1; tj = tp - 3; }
  else if (tp < 9) { ti = 2; tj = tp - 5; }
  else             { ti = 3; tj = 3; }
  __shared__ float E1[64][65], E2[64][65];
  __shared__ float mI[64], mJ[64];
  const int t = threadIdx.x;
  const int i0 = ti*64, j0 = tj*64, base = b << 16;
  for (int idx = t; idx < 4096; idx += 256) {
    const int r = idx >> 6, c = idx & 63;
    E1[r][c] = e_raw[base + (i0 + r)*256 + j0 + c];
    E2[r][c] = e_raw[base + (j0 + r)*256 + i0 + c];
  }
  if (t < 64)       mI[t] = mask[b*256 + i0 + t];
  else if (t < 128) mJ[t-64] = mask[b*256 + j0 + (t-64)];
  __syncthreads();
  for (int idx = t; idx < 4096; idx += 256) {
    const int r = idx >> 6, c = idx & 63;
    const int i = i0 + r, j = j0 + c;
    float v = 1000000.0f;
    if ((mI[r]*mJ[c] > 0.5f) && (i != j)) v = 0.5f*(E1[r][c] + E2[c][r]);
    out[524288 + base + i*256 + j] = v;
  }
  if (ti != tj) {
    for (int idx = t; idx < 4096; idx += 256) {
      const int r = idx >> 6, c = idx & 63;
      float v = 1000000.0f;
      if (mJ[r]*mI[c] > 0.5f) v = 0.5f*(E2[r][c] + E1[c][r]);
      out[524288 + base + (j0 + r)*256 + i0 + c] = v;
    }
  }
}

extern "C" void kernel_launch(void* const* d_in, const int* in_sizes, int n_in,
                              void* d_out, int out_size, void* d_ws, size_t ws_size,
                              hipStream_t stream) {
  const float* af   = (const float*)d_in[0];
  const float* zm   = (const float*)d_in[1];
  const float* zlv  = (const float*)d_in[2];
  const float* mask = (const float*)d_in[3];
  const float* W1d  = (const float*)d_in[4];
  const float* b1d  = (const float*)d_in[5];
  const float* W2d  = (const float*)d_in[6];
  const float* b2d  = (const float*)d_in[7];
  const float* W3d  = (const float*)d_in[8];
  const float* b3d  = (const float*)d_in[9];
  const float* W1n  = (const float*)d_in[10];
  const float* b1n  = (const float*)d_in[11];
  const float* W2n  = (const float*)d_in[12];
  const float* b2n  = (const float*)d_in[13];
  const float* W3n  = (const float*)d_in[14];
  const float* b3n  = (const float*)d_in[15];

  u16*   ws16  = (u16*)d_ws;
  float* e_raw = (float*)((char*)d_ws + ERAW);
  float* out   = (float*)d_out;

  k_uvw<<<dim3(257, 2), 256, 0, stream>>>(af, zm, zlv, W1d, b1d, W1n, b1n, W2d, W2n, ws16);
  k_main<<<dim3(32, 2, 8), 256, 0, stream>>>(af, mask, W1d, b2d, W3d, b3d,
                                             W1n, b2n, W3n, b3n, ws16, e_raw, out);
  k_sym<<<dim3(10, 8), 256, 0, stream>>>(e_raw, mask, out);
}